// Round 8
// baseline (182.776 us; speedup 1.0000x reference)
//
#include <hip/hip_runtime.h>
#include <hip/hip_bf16.h>
#include <math.h>

// Problem: B=2, N=8192, M=8192, C=3, k=20; MLP 20->256->128->1 with BN+ReLU, sigmoid.
// Pipeline (3 launches):
//   k_prep : y -> 4 SoA planes (y0, y1, y2, -|y|^2) per batch + W2 transpose.
//   k_knn  : top-20 LARGEST pd = 2x.y - xx - yy. Query-group of 4 rows is
//            handled by a PAIR of waves, each scanning a contiguous half of
//            the 8192 candidates (candidate-split -> 8192 waves = 8/SIMD
//            resident; restores R2's latency-hiding regime). Per wave:
//            packed-f32 distance from 4-plane float4 loads (4 cands/load),
//            per-lane sorted top-4 (3 med3 + 1 max), register-only 20-round
//            half-merge with exactness guard (pops>=4 -> exact 20-deep redo
//            of the half). The two half top-20 lists are merged EXACTLY with
//            the parallel merge-path formula (no serial rounds):
//              out[r] = max(A[r], B[r], max_{j<r} min(A[j], B[r-1-j]))
//   k_mlp  : fused MLP, 32 rows/block, h1 in LDS. W2T from global (wave-
//            broadcast coalesced, L2-hot). bn2+relu+W3 dot in-wave; sigmoid.

#define M_CAND 8192
#define NROWS 16384
#define KSEL 20
#define MPL 4            // per-lane list length (main path)
#define RPW 4            // query rows per wave

typedef float v2f __attribute__((ext_vector_type(2)));

__device__ __forceinline__ float med3f(float a, float b, float c) {
    return __builtin_amdgcn_fmed3f(a, b, c);
}

__device__ __forceinline__ v2f fma2(v2f a, v2f b, v2f c) {
#if __has_builtin(__builtin_elementwise_fma)
    return __builtin_elementwise_fma(a, b, c);
#else
    v2f r; r.x = fmaf(a.x, b.x, c.x); r.y = fmaf(a.y, b.y, c.y); return r;
#endif
}

// ---------- kernel: prep (y planes + W2 transpose) ----------
__global__ __launch_bounds__(256) void k_prep(const float* __restrict__ y,
                                              const float* __restrict__ w2,
                                              float* __restrict__ ys,
                                              float* __restrict__ w2t) {
    int idx = blockIdx.x * 256 + threadIdx.x;     // 49152 total
    if (idx < NROWS) {                            // 16384 candidate points
        int b = idx >> 13, m = idx & 8191;
        const float* p = y + (size_t)idx * 3;
        float y0 = p[0], y1 = p[1], y2 = p[2];
        float* base = ys + (size_t)b * 4 * M_CAND + m;
        base[0]          = y0;
        base[M_CAND]     = y1;
        base[2 * M_CAND] = y2;
        base[3 * M_CAND] = -(y0 * y0 + y1 * y1 + y2 * y2);
    } else {
        int j = idx - NROWS;                      // 32768 W2 elements
        int o = j >> 8, kk = j & 255;
        w2t[kk * 128 + o] = w2[j];
    }
}

// ---------- kernel: kNN top-20 (wave-pair candidate split, 4 q/wave) ----------
__global__ __launch_bounds__(256, 8) void k_knn(const float* __restrict__ x,
                                                const float* __restrict__ ys,
                                                float* __restrict__ dfeat) {
    __shared__ float mxbuf[2][RPW][2][KSEL];      // [group][q][half][rank], 1.3KB
    const int tid  = threadIdx.x;
    const int wid  = tid >> 6;
    const int lane = tid & 63;
    const int g    = wid >> 1;                    // query group within block (0..1)
    const int h    = wid & 1;                     // candidate half (0..1)
    const int qbase = blockIdx.x * 8 + g * 4;     // grid 2048 -> 16384 rows
    const int b = qbase >> 13;

    float tx0[RPW], tx1[RPW], tx2[RPW], xxn[RPW];
#pragma unroll
    for (int r = 0; r < RPW; ++r) {
        float a0 = x[(qbase + r) * 3 + 0];
        float a1 = x[(qbase + r) * 3 + 1];
        float a2 = x[(qbase + r) * 3 + 2];
        tx0[r] = 2.0f * a0; tx1[r] = 2.0f * a1; tx2[r] = 2.0f * a2;
        xxn[r] = -(a0 * a0 + a1 * a1 + a2 * a2);
    }
    const float4* q0 = (const float4*)(ys + (size_t)(b * 4 + 0) * M_CAND);
    const float4* q1 = (const float4*)(ys + (size_t)(b * 4 + 1) * M_CAND);
    const float4* q2 = (const float4*)(ys + (size_t)(b * 4 + 2) * M_CAND);
    const float4* q3 = (const float4*)(ys + (size_t)(b * 4 + 3) * M_CAND);
    const int hbase = h * 1024;                   // my half: 1024 float4 groups

    // descending per-lane top-4 of pd per query (over my 4096 candidates)
    float bl[RPW][MPL];
#pragma unroll
    for (int r = 0; r < RPW; ++r)
#pragma unroll
        for (int j = 0; j < MPL; ++j) bl[r][j] = -3.0e38f;

    // main loop: 16 iters x 4 cands/lane; 4 plane loads serve 4 queries
#pragma unroll 1
    for (int t = 0; t < 16; ++t) {
        const int idx = hbase + t * 64 + lane;
        float4 A0 = q0[idx], A1 = q1[idx], A2 = q2[idx], A3 = q3[idx];
        v2f y0a = {A0.x, A0.y}, y0b = {A0.z, A0.w};
        v2f y1a = {A1.x, A1.y}, y1b = {A1.z, A1.w};
        v2f y2a = {A2.x, A2.y}, y2b = {A2.z, A2.w};
        v2f nwa = {A3.x, A3.y}, nwb = {A3.z, A3.w};
#pragma unroll
        for (int r = 0; r < RPW; ++r) {
            v2f t0 = {tx0[r], tx0[r]};
            v2f t1 = {tx1[r], tx1[r]};
            v2f t2 = {tx2[r], tx2[r]};
            v2f xp = {xxn[r], xxn[r]};
            v2f pa = fma2(t0, y0a, fma2(t1, y1a, fma2(t2, y2a, xp))) + nwa;
            v2f pb = fma2(t0, y0b, fma2(t1, y1b, fma2(t2, y2b, xp))) + nwb;
            float v0 = pa.x, v1 = pa.y, v2v = pb.x, v3 = pb.y;
            bl[r][3] = med3f(v0, bl[r][2], bl[r][3]);
            bl[r][2] = med3f(v0, bl[r][1], bl[r][2]);
            bl[r][1] = med3f(v0, bl[r][0], bl[r][1]);
            bl[r][0] = fmaxf(bl[r][0], v0);
            bl[r][3] = med3f(v1, bl[r][2], bl[r][3]);
            bl[r][2] = med3f(v1, bl[r][1], bl[r][2]);
            bl[r][1] = med3f(v1, bl[r][0], bl[r][1]);
            bl[r][0] = fmaxf(bl[r][0], v1);
            bl[r][3] = med3f(v2v, bl[r][2], bl[r][3]);
            bl[r][2] = med3f(v2v, bl[r][1], bl[r][2]);
            bl[r][1] = med3f(v2v, bl[r][0], bl[r][1]);
            bl[r][0] = fmaxf(bl[r][0], v2v);
            bl[r][3] = med3f(v3, bl[r][2], bl[r][3]);
            bl[r][2] = med3f(v3, bl[r][1], bl[r][2]);
            bl[r][1] = med3f(v3, bl[r][0], bl[r][1]);
            bl[r][0] = fmaxf(bl[r][0], v3);
        }
    }

    // register-only half-merge: 20 rounds of wave-max; winner lane shifts.
    float selv[RPW];
    unsigned needmask = 0;
#pragma unroll
    for (int q = 0; q < RPW; ++q) {
        float h0 = bl[q][0], h1 = bl[q][1], h2 = bl[q][2], h3 = bl[q][3];
        int pops = 0;
        float sel = 0.0f;
        for (int r = 0; r < KSEL; ++r) {
            float mx = h0;
#pragma unroll
            for (int off = 32; off >= 1; off >>= 1) mx = fmaxf(mx, __shfl_xor(mx, off, 64));
            unsigned long long ball = __ballot(h0 == mx);
            int winner = (int)__ffsll(ball) - 1;  // first lane holding max (tie-safe)
            bool win = (lane == winner);
            h0 = win ? h1 : h0;
            h1 = win ? h2 : h1;
            h2 = win ? h3 : h2;
            h3 = win ? -3.0e38f : h3;
            pops += win ? 1 : 0;
            if (lane == r) sel = mx;
        }
        if (__ballot(pops >= MPL) != 0ULL) needmask |= (1u << q);
        selv[q] = sel;
    }

    // exactness fallback: redo flagged (query, my-half) with 20-deep chain
    if (needmask != 0) {
#pragma unroll
        for (int q = 0; q < RPW; ++q) {
            if (!(needmask & (1u << q))) continue;
            float a[KSEL];
#pragma unroll
            for (int j = 0; j < KSEL; ++j) a[j] = -3.0e38f;
#pragma unroll 1
            for (int t = 0; t < 16; ++t) {
                const int idx = hbase + t * 64 + lane;
                float4 A0 = q0[idx], A1 = q1[idx], A2 = q2[idx], A3 = q3[idx];
                const float* e0 = (const float*)&A0;
                const float* e1 = (const float*)&A1;
                const float* e2 = (const float*)&A2;
                const float* e3 = (const float*)&A3;
#pragma unroll
                for (int i = 0; i < 4; ++i) {
                    float v = fmaf(tx0[q], e0[i], fmaf(tx1[q], e1[i],
                              fmaf(tx2[q], e2[i], xxn[q]))) + e3[i];
#pragma unroll
                    for (int jj = KSEL - 1; jj >= 1; --jj) a[jj] = med3f(v, a[jj - 1], a[jj]);
                    a[0] = fmaxf(a[0], v);
                }
            }
            float sel2 = 0.0f;
            for (int r = 0; r < KSEL; ++r) {
                float mx = a[0];
#pragma unroll
                for (int off = 32; off >= 1; off >>= 1) mx = fmaxf(mx, __shfl_xor(mx, off, 64));
                unsigned long long ball = __ballot(a[0] == mx);
                int winner = (int)__ffsll(ball) - 1;
                bool win = (lane == winner);
#pragma unroll
                for (int jj = 0; jj < KSEL - 1; ++jj) a[jj] = win ? a[jj + 1] : a[jj];
                a[KSEL - 1] = win ? -3.0e38f : a[KSEL - 1];
                if (lane == r) sel2 = mx;
            }
            selv[q] = sel2;
        }
    }

    // exchange half top-20 lists through LDS
#pragma unroll
    for (int q = 0; q < RPW; ++q)
        if (lane < KSEL) mxbuf[g][q][h][lane] = selv[q];
    __syncthreads();

    // exact final merge of two sorted-desc 20-lists (merge-path formula):
    // out[r] = max(A[r], B[r], max_{j<r} min(A[j], B[r-1-j])). Wave h does
    // queries {2h, 2h+1} of its group.
#pragma unroll
    for (int qq = 0; qq < 2; ++qq) {
        const int q = h * 2 + qq;
        float vA = (lane < KSEL) ? mxbuf[g][q][0][lane] : -3.0e38f;
        float vB = (lane < KSEL) ? mxbuf[g][q][1][lane] : -3.0e38f;
        float m = fmaxf(vA, vB);
#pragma unroll
        for (int j = 0; j < KSEL - 1; ++j) {
            float aj = __shfl(vA, j, 64);
            float bj = __shfl(vB, (lane - 1 - j) & 63, 64);
            float t = fminf(aj, bj);
            m = (j < lane) ? fmaxf(m, t) : m;
        }
        if (lane < KSEL) dfeat[(size_t)(qbase + q) * KSEL + lane] = m;
    }
}

// ---------- kernel: fused MLP (bn1/relu -> GEMM2 -> bn2/relu -> W3 -> sigmoid) ----------
__global__ __launch_bounds__(256) void k_mlp(const float* __restrict__ dfeat,
                                             const float* __restrict__ W1,
                                             const float* __restrict__ g1,
                                             const float* __restrict__ be1,
                                             const float* __restrict__ mu1,
                                             const float* __restrict__ va1,
                                             const float* __restrict__ W2T,
                                             const float* __restrict__ g2,
                                             const float* __restrict__ be2,
                                             const float* __restrict__ mu2,
                                             const float* __restrict__ va2,
                                             const float* __restrict__ W3,
                                             float* __restrict__ out) {
    __shared__ float h1l[32 * 260];               // 33,280 B (stride 260: conflict-free)
    const int t = threadIdx.x;
    const int rowbase = blockIdx.x * 32;          // grid 512 -> all 16384 rows

    float w[KSEL];
#pragma unroll
    for (int j = 0; j < KSEL; j += 4) {
        float4 q = *(const float4*)(W1 + t * KSEL + j);
        w[j] = q.x; w[j + 1] = q.y; w[j + 2] = q.z; w[j + 3] = q.w;
    }
    const float s1  = g1[t] * rsqrtf(va1[t] + 1e-5f);
    const float bc1 = be1[t] - mu1[t] * s1;

    for (int r = 0; r < 32; ++r) {
        const float* dr = dfeat + (size_t)(rowbase + r) * KSEL;
        float dv[KSEL];
#pragma unroll
        for (int j = 0; j < KSEL; j += 4) {
            float4 q = *(const float4*)(dr + j);
            dv[j] = q.x; dv[j + 1] = q.y; dv[j + 2] = q.z; dv[j + 3] = q.w;
        }
        float acc0 = 0.f, acc1 = 0.f;
#pragma unroll
        for (int j = 0; j < KSEL; j += 2) {
            acc0 = fmaf(w[j], dv[j], acc0);
            acc1 = fmaf(w[j + 1], dv[j + 1], acc1);
        }
        h1l[r * 260 + t] = fmaxf(0.f, fmaf(s1, acc0 + acc1, bc1));
    }
    __syncthreads();

    const int og = t & 15;
    const int rq = t >> 4;
    float acc[2][8];
#pragma unroll
    for (int r = 0; r < 2; ++r)
#pragma unroll
        for (int i = 0; i < 8; ++i) acc[r][i] = 0.f;

    for (int kq = 0; kq < 64; ++kq) {
        const int k = kq * 4;
        float4 hq[2];
#pragma unroll
        for (int rr = 0; rr < 2; ++rr)
            hq[rr] = *(const float4*)(&h1l[(rq * 2 + rr) * 260 + k]);
        float4 wq[8];
#pragma unroll
        for (int kk = 0; kk < 4; ++kk) {
            wq[kk]     = *(const float4*)(W2T + (k + kk) * 128 + og * 4);
            wq[4 + kk] = *(const float4*)(W2T + (k + kk) * 128 + 64 + og * 4);
        }
#pragma unroll
        for (int r = 0; r < 2; ++r) {
            const float* hh = (const float*)&hq[r];
#pragma unroll
            for (int kk = 0; kk < 4; ++kk) {
                const float hval = hh[kk];
                const float* w0 = (const float*)&wq[kk];
                const float* w1 = (const float*)&wq[4 + kk];
#pragma unroll
                for (int i = 0; i < 4; ++i) {
                    acc[r][i]     = fmaf(hval, w0[i], acc[r][i]);
                    acc[r][4 + i] = fmaf(hval, w1[i], acc[r][4 + i]);
                }
            }
        }
    }

    float s2v[8], b2v[8], w3v[8];
#pragma unroll
    for (int hh = 0; hh < 2; ++hh)
#pragma unroll
        for (int i = 0; i < 4; ++i) {
            const int o = hh * 64 + og * 4 + i;
            const float sv = g2[o] * rsqrtf(va2[o] + 1e-5f);
            s2v[hh * 4 + i] = sv;
            b2v[hh * 4 + i] = be2[o] - mu2[o] * sv;
            w3v[hh * 4 + i] = W3[o];
        }
#pragma unroll
    for (int r = 0; r < 2; ++r) {
        float c = 0.f;
#pragma unroll
        for (int i = 0; i < 8; ++i) {
            float h2 = fmaxf(0.f, fmaf(s2v[i], acc[r][i], b2v[i]));
            c = fmaf(w3v[i], h2, c);
        }
#pragma unroll
        for (int off = 8; off >= 1; off >>= 1) c += __shfl_xor(c, off, 64);
        if (og == 0) {
            out[rowbase + rq * 2 + r] = 1.0f / (1.0f + expf(-c));
        }
    }
}

extern "C" void kernel_launch(void* const* d_in, const int* in_sizes, int n_in,
                              void* d_out, int out_size, void* d_ws, size_t ws_size,
                              hipStream_t stream) {
    const float* x   = (const float*)d_in[0];
    const float* y   = (const float*)d_in[1];
    const float* W1  = (const float*)d_in[2];
    const float* g1  = (const float*)d_in[3];
    const float* be1 = (const float*)d_in[4];
    const float* mu1 = (const float*)d_in[5];
    const float* va1 = (const float*)d_in[6];
    const float* W2  = (const float*)d_in[7];
    const float* g2  = (const float*)d_in[8];
    const float* be2 = (const float*)d_in[9];
    const float* mu2 = (const float*)d_in[10];
    const float* va2 = (const float*)d_in[11];
    const float* W3  = (const float*)d_in[12];
    float* out = (float*)d_out;

    char* ws = (char*)d_ws;
    float* ys    = (float*)(ws);                                    // 262,144 B
    float* dfeat = (float*)(ws + 262144);                           // 1,310,720 B
    float* w2t   = (float*)(ws + 262144 + 1310720);                 // 131,072 B

    k_prep<<<192, 256, 0, stream>>>(y, W2, ys, w2t);
    k_knn <<<2048, 256, 0, stream>>>(x, ys, dfeat);
    k_mlp <<<512, 256, 0, stream>>>(dfeat, W1, g1, be1, mu1, va1,
                                    w2t, g2, be2, mu2, va2, W3, out);
}

// Round 9
// 129.190 us; speedup vs baseline: 1.4148x; 1.4148x over previous
//
#include <hip/hip_runtime.h>
#include <hip/hip_bf16.h>
#include <math.h>

// Problem: B=2, N=8192, M=8192, C=3, k=20; MLP 20->256->128->1 with BN+ReLU, sigmoid.
// Pipeline (3 launches):
//   k_prep : y -> 4 SoA planes (y0, y1, y2, -|y|^2) per batch + W2 transpose.
//   k_knn  : top-20 LARGEST pd = 2x.y - xx - yy. 2 queries per wave (shares
//            candidate loads; halves L2 traffic vs 1 q/wave), 8 queries/block,
//            grid 2048 -> 8192 waves = 32/CU resident (the R2-proven
//            high-occupancy regime; NO launch_bounds min-waves hint, NO LDS).
//            Packed-f32 distance (4 plane float4 loads -> 4 cands x 2 queries),
//            per-lane sorted top-4 (3 med3 + 1 max), register-only 20-round
//            merge (winner lane shifts its 4-deep list). Exactness guard:
//            lane pops all 4 slots -> register 20-deep redo (cold path;
//            R5 proved the compiler overlays it on dead main-loop regs).
//   k_mlp  : fused MLP, 32 rows/block, h1 in LDS. W2T from global (L2-hot).
//            bn2+relu+W3 dot in-wave; sigmoid.

#define M_CAND 8192
#define NROWS 16384
#define KSEL 20
#define MPL 4            // per-lane list length (main path)
#define RPW 2            // query rows per wave

typedef float v2f __attribute__((ext_vector_type(2)));

__device__ __forceinline__ float med3f(float a, float b, float c) {
    return __builtin_amdgcn_fmed3f(a, b, c);
}

__device__ __forceinline__ v2f fma2(v2f a, v2f b, v2f c) {
#if __has_builtin(__builtin_elementwise_fma)
    return __builtin_elementwise_fma(a, b, c);
#else
    v2f r; r.x = fmaf(a.x, b.x, c.x); r.y = fmaf(a.y, b.y, c.y); return r;
#endif
}

// ---------- kernel: prep (y planes + W2 transpose) ----------
__global__ __launch_bounds__(256) void k_prep(const float* __restrict__ y,
                                              const float* __restrict__ w2,
                                              float* __restrict__ ys,
                                              float* __restrict__ w2t) {
    int idx = blockIdx.x * 256 + threadIdx.x;     // 49152 total
    if (idx < NROWS) {                            // 16384 candidate points
        int b = idx >> 13, m = idx & 8191;
        const float* p = y + (size_t)idx * 3;
        float y0 = p[0], y1 = p[1], y2 = p[2];
        float* base = ys + (size_t)b * 4 * M_CAND + m;
        base[0]          = y0;
        base[M_CAND]     = y1;
        base[2 * M_CAND] = y2;
        base[3 * M_CAND] = -(y0 * y0 + y1 * y1 + y2 * y2);
    } else {
        int j = idx - NROWS;                      // 32768 W2 elements
        int o = j >> 8, kk = j & 255;
        w2t[kk * 128 + o] = w2[j];
    }
}

// ---------- kernel: kNN top-20 (2 queries/wave, register-only select) ----------
__global__ __launch_bounds__(256) void k_knn(const float* __restrict__ x,
                                             const float* __restrict__ ys,
                                             float* __restrict__ dfeat) {
    const int tid  = threadIdx.x;
    const int wid  = tid >> 6;
    const int lane = tid & 63;
    const int qbase = blockIdx.x * 8 + wid * RPW; // grid 2048 -> 16384 rows
    const int b = qbase >> 13;

    float tx0[RPW], tx1[RPW], tx2[RPW], xxn[RPW];
#pragma unroll
    for (int r = 0; r < RPW; ++r) {
        float a0 = x[(qbase + r) * 3 + 0];
        float a1 = x[(qbase + r) * 3 + 1];
        float a2 = x[(qbase + r) * 3 + 2];
        tx0[r] = 2.0f * a0; tx1[r] = 2.0f * a1; tx2[r] = 2.0f * a2;
        xxn[r] = -(a0 * a0 + a1 * a1 + a2 * a2);
    }
    const float4* q0 = (const float4*)(ys + (size_t)(b * 4 + 0) * M_CAND);
    const float4* q1 = (const float4*)(ys + (size_t)(b * 4 + 1) * M_CAND);
    const float4* q2 = (const float4*)(ys + (size_t)(b * 4 + 2) * M_CAND);
    const float4* q3 = (const float4*)(ys + (size_t)(b * 4 + 3) * M_CAND);

    // descending per-lane top-4 of pd per query
    float bl[RPW][MPL];
#pragma unroll
    for (int r = 0; r < RPW; ++r)
#pragma unroll
        for (int j = 0; j < MPL; ++j) bl[r][j] = -3.0e38f;

    // main loop: 32 iters x 4 cands/lane; 4 plane loads serve both queries
#pragma unroll 1
    for (int t = 0; t < 32; ++t) {
        const int idx = t * 64 + lane;
        float4 A0 = q0[idx], A1 = q1[idx], A2 = q2[idx], A3 = q3[idx];
        v2f y0a = {A0.x, A0.y}, y0b = {A0.z, A0.w};
        v2f y1a = {A1.x, A1.y}, y1b = {A1.z, A1.w};
        v2f y2a = {A2.x, A2.y}, y2b = {A2.z, A2.w};
        v2f nwa = {A3.x, A3.y}, nwb = {A3.z, A3.w};
#pragma unroll
        for (int r = 0; r < RPW; ++r) {
            v2f t0 = {tx0[r], tx0[r]};
            v2f t1 = {tx1[r], tx1[r]};
            v2f t2 = {tx2[r], tx2[r]};
            v2f xp = {xxn[r], xxn[r]};
            v2f pa = fma2(t0, y0a, fma2(t1, y1a, fma2(t2, y2a, xp))) + nwa;
            v2f pb = fma2(t0, y0b, fma2(t1, y1b, fma2(t2, y2b, xp))) + nwb;
            float v0 = pa.x, v1 = pa.y, v2v = pb.x, v3 = pb.y;
            bl[r][3] = med3f(v0, bl[r][2], bl[r][3]);
            bl[r][2] = med3f(v0, bl[r][1], bl[r][2]);
            bl[r][1] = med3f(v0, bl[r][0], bl[r][1]);
            bl[r][0] = fmaxf(bl[r][0], v0);
            bl[r][3] = med3f(v1, bl[r][2], bl[r][3]);
            bl[r][2] = med3f(v1, bl[r][1], bl[r][2]);
            bl[r][1] = med3f(v1, bl[r][0], bl[r][1]);
            bl[r][0] = fmaxf(bl[r][0], v1);
            bl[r][3] = med3f(v2v, bl[r][2], bl[r][3]);
            bl[r][2] = med3f(v2v, bl[r][1], bl[r][2]);
            bl[r][1] = med3f(v2v, bl[r][0], bl[r][1]);
            bl[r][0] = fmaxf(bl[r][0], v2v);
            bl[r][3] = med3f(v3, bl[r][2], bl[r][3]);
            bl[r][2] = med3f(v3, bl[r][1], bl[r][2]);
            bl[r][1] = med3f(v3, bl[r][0], bl[r][1]);
            bl[r][0] = fmaxf(bl[r][0], v3);
        }
    }

    // register-only merge: 20 rounds of wave-max; winner lane shifts its list.
    unsigned needmask = 0;
#pragma unroll
    for (int q = 0; q < RPW; ++q) {
        float h0 = bl[q][0], h1 = bl[q][1], h2 = bl[q][2], h3 = bl[q][3];
        int pops = 0;
        float sel = 0.0f;
        for (int r = 0; r < KSEL; ++r) {
            float mx = h0;
#pragma unroll
            for (int off = 32; off >= 1; off >>= 1) mx = fmaxf(mx, __shfl_xor(mx, off, 64));
            unsigned long long ball = __ballot(h0 == mx);
            int winner = (int)__ffsll(ball) - 1;  // first lane holding max (tie-safe)
            bool win = (lane == winner);
            h0 = win ? h1 : h0;
            h1 = win ? h2 : h1;
            h2 = win ? h3 : h2;
            h3 = win ? -3.0e38f : h3;
            pops += win ? 1 : 0;
            if (lane == r) sel = mx;
        }
        if (__ballot(pops >= MPL) != 0ULL) needmask |= (1u << q);
        if (lane < KSEL) dfeat[(size_t)(qbase + q) * KSEL + lane] = sel;
    }

    // exactness fallback (cold, ~1% of waves): register 20-deep redo per
    // flagged query; compiler overlays a[] on dead main-loop registers (R5).
    if (needmask != 0) {
#pragma unroll
        for (int q = 0; q < RPW; ++q) {
            if (!(needmask & (1u << q))) continue;
            float a[KSEL];
#pragma unroll
            for (int j = 0; j < KSEL; ++j) a[j] = -3.0e38f;
#pragma unroll 1
            for (int t = 0; t < 32; ++t) {
                const int idx = t * 64 + lane;
                float4 A0 = q0[idx], A1 = q1[idx], A2 = q2[idx], A3 = q3[idx];
                const float* e0 = (const float*)&A0;
                const float* e1 = (const float*)&A1;
                const float* e2 = (const float*)&A2;
                const float* e3 = (const float*)&A3;
#pragma unroll
                for (int i = 0; i < 4; ++i) {
                    float v = fmaf(tx0[q], e0[i], fmaf(tx1[q], e1[i],
                              fmaf(tx2[q], e2[i], xxn[q]))) + e3[i];
#pragma unroll
                    for (int jj = KSEL - 1; jj >= 1; --jj) a[jj] = med3f(v, a[jj - 1], a[jj]);
                    a[0] = fmaxf(a[0], v);
                }
            }
            float sel2 = 0.0f;
            for (int r = 0; r < KSEL; ++r) {
                float mx = a[0];
#pragma unroll
                for (int off = 32; off >= 1; off >>= 1) mx = fmaxf(mx, __shfl_xor(mx, off, 64));
                unsigned long long ball = __ballot(a[0] == mx);
                int winner = (int)__ffsll(ball) - 1;
                bool win = (lane == winner);
#pragma unroll
                for (int jj = 0; jj < KSEL - 1; ++jj) a[jj] = win ? a[jj + 1] : a[jj];
                a[KSEL - 1] = win ? -3.0e38f : a[KSEL - 1];
                if (lane == r) sel2 = mx;
            }
            if (lane < KSEL) dfeat[(size_t)(qbase + q) * KSEL + lane] = sel2;
        }
    }
}

// ---------- kernel: fused MLP (bn1/relu -> GEMM2 -> bn2/relu -> W3 -> sigmoid) ----------
__global__ __launch_bounds__(256) void k_mlp(const float* __restrict__ dfeat,
                                             const float* __restrict__ W1,
                                             const float* __restrict__ g1,
                                             const float* __restrict__ be1,
                                             const float* __restrict__ mu1,
                                             const float* __restrict__ va1,
                                             const float* __restrict__ W2T,
                                             const float* __restrict__ g2,
                                             const float* __restrict__ be2,
                                             const float* __restrict__ mu2,
                                             const float* __restrict__ va2,
                                             const float* __restrict__ W3,
                                             float* __restrict__ out) {
    __shared__ float h1l[32 * 260];               // 33,280 B (stride 260: conflict-free)
    const int t = threadIdx.x;
    const int rowbase = blockIdx.x * 32;          // grid 512 -> all 16384 rows

    float w[KSEL];
#pragma unroll
    for (int j = 0; j < KSEL; j += 4) {
        float4 q = *(const float4*)(W1 + t * KSEL + j);
        w[j] = q.x; w[j + 1] = q.y; w[j + 2] = q.z; w[j + 3] = q.w;
    }
    const float s1  = g1[t] * rsqrtf(va1[t] + 1e-5f);
    const float bc1 = be1[t] - mu1[t] * s1;

    for (int r = 0; r < 32; ++r) {
        const float* dr = dfeat + (size_t)(rowbase + r) * KSEL;
        float dv[KSEL];
#pragma unroll
        for (int j = 0; j < KSEL; j += 4) {
            float4 q = *(const float4*)(dr + j);
            dv[j] = q.x; dv[j + 1] = q.y; dv[j + 2] = q.z; dv[j + 3] = q.w;
        }
        float acc0 = 0.f, acc1 = 0.f;
#pragma unroll
        for (int j = 0; j < KSEL; j += 2) {
            acc0 = fmaf(w[j], dv[j], acc0);
            acc1 = fmaf(w[j + 1], dv[j + 1], acc1);
        }
        h1l[r * 260 + t] = fmaxf(0.f, fmaf(s1, acc0 + acc1, bc1));
    }
    __syncthreads();

    const int og = t & 15;
    const int rq = t >> 4;
    float acc[2][8];
#pragma unroll
    for (int r = 0; r < 2; ++r)
#pragma unroll
        for (int i = 0; i < 8; ++i) acc[r][i] = 0.f;

    for (int kq = 0; kq < 64; ++kq) {
        const int k = kq * 4;
        float4 hq[2];
#pragma unroll
        for (int rr = 0; rr < 2; ++rr)
            hq[rr] = *(const float4*)(&h1l[(rq * 2 + rr) * 260 + k]);
        float4 wq[8];
#pragma unroll
        for (int kk = 0; kk < 4; ++kk) {
            wq[kk]     = *(const float4*)(W2T + (k + kk) * 128 + og * 4);
            wq[4 + kk] = *(const float4*)(W2T + (k + kk) * 128 + 64 + og * 4);
        }
#pragma unroll
        for (int r = 0; r < 2; ++r) {
            const float* hh = (const float*)&hq[r];
#pragma unroll
            for (int kk = 0; kk < 4; ++kk) {
                const float hval = hh[kk];
                const float* w0 = (const float*)&wq[kk];
                const float* w1 = (const float*)&wq[4 + kk];
#pragma unroll
                for (int i = 0; i < 4; ++i) {
                    acc[r][i]     = fmaf(hval, w0[i], acc[r][i]);
                    acc[r][4 + i] = fmaf(hval, w1[i], acc[r][4 + i]);
                }
            }
        }
    }

    float s2v[8], b2v[8], w3v[8];
#pragma unroll
    for (int hh = 0; hh < 2; ++hh)
#pragma unroll
        for (int i = 0; i < 4; ++i) {
            const int o = hh * 64 + og * 4 + i;
            const float sv = g2[o] * rsqrtf(va2[o] + 1e-5f);
            s2v[hh * 4 + i] = sv;
            b2v[hh * 4 + i] = be2[o] - mu2[o] * sv;
            w3v[hh * 4 + i] = W3[o];
        }
#pragma unroll
    for (int r = 0; r < 2; ++r) {
        float c = 0.f;
#pragma unroll
        for (int i = 0; i < 8; ++i) {
            float h2 = fmaxf(0.f, fmaf(s2v[i], acc[r][i], b2v[i]));
            c = fmaf(w3v[i], h2, c);
        }
#pragma unroll
        for (int off = 8; off >= 1; off >>= 1) c += __shfl_xor(c, off, 64);
        if (og == 0) {
            out[rowbase + rq * 2 + r] = 1.0f / (1.0f + expf(-c));
        }
    }
}

extern "C" void kernel_launch(void* const* d_in, const int* in_sizes, int n_in,
                              void* d_out, int out_size, void* d_ws, size_t ws_size,
                              hipStream_t stream) {
    const float* x   = (const float*)d_in[0];
    const float* y   = (const float*)d_in[1];
    const float* W1  = (const float*)d_in[2];
    const float* g1  = (const float*)d_in[3];
    const float* be1 = (const float*)d_in[4];
    const float* mu1 = (const float*)d_in[5];
    const float* va1 = (const float*)d_in[6];
    const float* W2  = (const float*)d_in[7];
    const float* g2  = (const float*)d_in[8];
    const float* be2 = (const float*)d_in[9];
    const float* mu2 = (const float*)d_in[10];
    const float* va2 = (const float*)d_in[11];
    const float* W3  = (const float*)d_in[12];
    float* out = (float*)d_out;

    char* ws = (char*)d_ws;
    float* ys    = (float*)(ws);                                    // 262,144 B
    float* dfeat = (float*)(ws + 262144);                           // 1,310,720 B
    float* w2t   = (float*)(ws + 262144 + 1310720);                 // 131,072 B

    k_prep<<<192, 256, 0, stream>>>(y, W2, ys, w2t);
    k_knn <<<2048, 256, 0, stream>>>(x, ys, dfeat);
    k_mlp <<<512, 256, 0, stream>>>(dfeat, W1, g1, be1, mu1, va1,
                                    w2t, g2, be2, mu2, va2, W3, out);
}

// Round 10
// 126.416 us; speedup vs baseline: 1.4458x; 1.0219x over previous
//
#include <hip/hip_runtime.h>
#include <hip/hip_bf16.h>
#include <math.h>

// Problem: B=2, N=8192, M=8192, C=3, k=20; MLP 20->256->128->1 with BN+ReLU, sigmoid.
// Pipeline (3 launches):
//   k_prep : y -> 4 SoA planes (y0, y1, y2, -|y|^2) per batch + W2 transpose.
//   k_knn  : top-20 LARGEST pd = 2x.y - xx - yy.
//            Structure: wave-PAIR splits the 8192 candidates in half; each
//            wave serves 2 queries (RPW=2) over its 4096 candidates.
//            Block = 4 waves = 2 pairs = 4 queries -> grid 4096 = 16384 waves
//            = 2x oversubscribed (R2-proven regime: scan-phase waves backfill
//            merge-phase latency). NO launch_bounds min-waves hint (R8 lesson:
//            forcing 8/SIMD spilled everything to scratch).
//            Per wave: packed-f32 distance (4 plane float4 loads -> 4 cands x
//            2 queries), per-lane sorted top-4 (3 med3 + 1 max), 20-round
//            register half-merge with BOTH queries' rounds interleaved (two
//            independent shuffle chains co-issue -> half the exposed latency).
//            Exactness guard: lane pops all 4 slots -> register 20-deep redo
//            of the half (cold). Halves exchanged via 640B LDS; final exact
//            merge of two sorted 20-lists via parallel merge-path formula:
//              out[r] = max(A[r], B[r], max_{j<r} min(A[j], B[r-1-j]))
//   k_mlp  : fused MLP, 32 rows/block, h1 in LDS. W2T from global (L2-hot).
//            bn2+relu+W3 dot in-wave; sigmoid.

#define M_CAND 8192
#define NROWS 16384
#define KSEL 20
#define MPL 4            // per-lane list length (main path)

typedef float v2f __attribute__((ext_vector_type(2)));

__device__ __forceinline__ float med3f(float a, float b, float c) {
    return __builtin_amdgcn_fmed3f(a, b, c);
}

__device__ __forceinline__ v2f fma2(v2f a, v2f b, v2f c) {
#if __has_builtin(__builtin_elementwise_fma)
    return __builtin_elementwise_fma(a, b, c);
#else
    v2f r; r.x = fmaf(a.x, b.x, c.x); r.y = fmaf(a.y, b.y, c.y); return r;
#endif
}

// ---------- kernel: prep (y planes + W2 transpose) ----------
__global__ __launch_bounds__(256) void k_prep(const float* __restrict__ y,
                                              const float* __restrict__ w2,
                                              float* __restrict__ ys,
                                              float* __restrict__ w2t) {
    int idx = blockIdx.x * 256 + threadIdx.x;     // 49152 total
    if (idx < NROWS) {                            // 16384 candidate points
        int b = idx >> 13, m = idx & 8191;
        const float* p = y + (size_t)idx * 3;
        float y0 = p[0], y1 = p[1], y2 = p[2];
        float* base = ys + (size_t)b * 4 * M_CAND + m;
        base[0]          = y0;
        base[M_CAND]     = y1;
        base[2 * M_CAND] = y2;
        base[3 * M_CAND] = -(y0 * y0 + y1 * y1 + y2 * y2);
    } else {
        int j = idx - NROWS;                      // 32768 W2 elements
        int o = j >> 8, kk = j & 255;
        w2t[kk * 128 + o] = w2[j];
    }
}

// ---------- kernel: kNN top-20 (wave-pair half-split, 2 q/wave) ----------
__global__ __launch_bounds__(256) void k_knn(const float* __restrict__ x,
                                             const float* __restrict__ ys,
                                             float* __restrict__ dfeat) {
    __shared__ float mxbuf[2][2][2][KSEL];        // [pair][q][half][rank], 640B
    const int tid  = threadIdx.x;
    const int wid  = tid >> 6;
    const int lane = tid & 63;
    const int p    = wid >> 1;                    // pair within block (0..1)
    const int h    = wid & 1;                     // candidate half (0..1)
    const int qbase = blockIdx.x * 4 + p * 2;     // grid 4096 -> 16384 rows
    const int b = (blockIdx.x * 4) >> 13;         // uniform per block

    float tx0[2], tx1[2], tx2[2], xxn[2];
#pragma unroll
    for (int r = 0; r < 2; ++r) {
        float a0 = x[(qbase + r) * 3 + 0];
        float a1 = x[(qbase + r) * 3 + 1];
        float a2 = x[(qbase + r) * 3 + 2];
        tx0[r] = 2.0f * a0; tx1[r] = 2.0f * a1; tx2[r] = 2.0f * a2;
        xxn[r] = -(a0 * a0 + a1 * a1 + a2 * a2);
    }
    const float4* q0 = (const float4*)(ys + (size_t)(b * 4 + 0) * M_CAND);
    const float4* q1 = (const float4*)(ys + (size_t)(b * 4 + 1) * M_CAND);
    const float4* q2 = (const float4*)(ys + (size_t)(b * 4 + 2) * M_CAND);
    const float4* q3 = (const float4*)(ys + (size_t)(b * 4 + 3) * M_CAND);
    const int hbase = h * 1024;                   // my half: 1024 float4/plane

    // descending per-lane top-4 of pd per query (over my 4096 candidates)
    float bl[2][MPL];
#pragma unroll
    for (int r = 0; r < 2; ++r)
#pragma unroll
        for (int j = 0; j < MPL; ++j) bl[r][j] = -3.0e38f;

    // scan: 16 iters x 4 cands/lane; 4 plane loads serve both queries
#pragma unroll 1
    for (int t = 0; t < 16; ++t) {
        const int idx = hbase + t * 64 + lane;
        float4 A0 = q0[idx], A1 = q1[idx], A2 = q2[idx], A3 = q3[idx];
        v2f y0a = {A0.x, A0.y}, y0b = {A0.z, A0.w};
        v2f y1a = {A1.x, A1.y}, y1b = {A1.z, A1.w};
        v2f y2a = {A2.x, A2.y}, y2b = {A2.z, A2.w};
        v2f nwa = {A3.x, A3.y}, nwb = {A3.z, A3.w};
#pragma unroll
        for (int r = 0; r < 2; ++r) {
            v2f t0 = {tx0[r], tx0[r]};
            v2f t1 = {tx1[r], tx1[r]};
            v2f t2 = {tx2[r], tx2[r]};
            v2f xp = {xxn[r], xxn[r]};
            v2f pa = fma2(t0, y0a, fma2(t1, y1a, fma2(t2, y2a, xp))) + nwa;
            v2f pb = fma2(t0, y0b, fma2(t1, y1b, fma2(t2, y2b, xp))) + nwb;
            float v0 = pa.x, v1 = pa.y, v2v = pb.x, v3 = pb.y;
            bl[r][3] = med3f(v0, bl[r][2], bl[r][3]);
            bl[r][2] = med3f(v0, bl[r][1], bl[r][2]);
            bl[r][1] = med3f(v0, bl[r][0], bl[r][1]);
            bl[r][0] = fmaxf(bl[r][0], v0);
            bl[r][3] = med3f(v1, bl[r][2], bl[r][3]);
            bl[r][2] = med3f(v1, bl[r][1], bl[r][2]);
            bl[r][1] = med3f(v1, bl[r][0], bl[r][1]);
            bl[r][0] = fmaxf(bl[r][0], v1);
            bl[r][3] = med3f(v2v, bl[r][2], bl[r][3]);
            bl[r][2] = med3f(v2v, bl[r][1], bl[r][2]);
            bl[r][1] = med3f(v2v, bl[r][0], bl[r][1]);
            bl[r][0] = fmaxf(bl[r][0], v2v);
            bl[r][3] = med3f(v3, bl[r][2], bl[r][3]);
            bl[r][2] = med3f(v3, bl[r][1], bl[r][2]);
            bl[r][1] = med3f(v3, bl[r][0], bl[r][1]);
            bl[r][0] = fmaxf(bl[r][0], v3);
        }
    }

    // half-merge: 20 rounds, BOTH queries interleaved (independent chains)
    float h0a = bl[0][0], h1a = bl[0][1], h2a = bl[0][2], h3a = bl[0][3];
    float h0b = bl[1][0], h1b = bl[1][1], h2b = bl[1][2], h3b = bl[1][3];
    int popsA = 0, popsB = 0;
    float selA = 0.0f, selB = 0.0f;
    for (int r = 0; r < KSEL; ++r) {
        float mxa = h0a, mxb = h0b;
#pragma unroll
        for (int off = 32; off >= 1; off >>= 1) {
            mxa = fmaxf(mxa, __shfl_xor(mxa, off, 64));
            mxb = fmaxf(mxb, __shfl_xor(mxb, off, 64));
        }
        unsigned long long ba = __ballot(h0a == mxa);
        unsigned long long bb = __ballot(h0b == mxb);
        bool winA = (lane == (int)__ffsll(ba) - 1);
        bool winB = (lane == (int)__ffsll(bb) - 1);
        h0a = winA ? h1a : h0a;  h0b = winB ? h1b : h0b;
        h1a = winA ? h2a : h1a;  h1b = winB ? h2b : h1b;
        h2a = winA ? h3a : h2a;  h2b = winB ? h3b : h2b;
        h3a = winA ? -3.0e38f : h3a;  h3b = winB ? -3.0e38f : h3b;
        popsA += winA ? 1 : 0;   popsB += winB ? 1 : 0;
        if (lane == r) { selA = mxa; selB = mxb; }
    }
    unsigned needmask = 0;
    if (__ballot(popsA >= MPL) != 0ULL) needmask |= 1u;
    if (__ballot(popsB >= MPL) != 0ULL) needmask |= 2u;

    // exactness fallback (cold): register 20-deep redo of my half per query
    if (needmask != 0) {
#pragma unroll
        for (int q = 0; q < 2; ++q) {
            if (!(needmask & (1u << q))) continue;
            float a[KSEL];
#pragma unroll
            for (int j = 0; j < KSEL; ++j) a[j] = -3.0e38f;
#pragma unroll 1
            for (int t = 0; t < 16; ++t) {
                const int idx = hbase + t * 64 + lane;
                float4 A0 = q0[idx], A1 = q1[idx], A2 = q2[idx], A3 = q3[idx];
                const float* e0 = (const float*)&A0;
                const float* e1 = (const float*)&A1;
                const float* e2 = (const float*)&A2;
                const float* e3 = (const float*)&A3;
#pragma unroll
                for (int i = 0; i < 4; ++i) {
                    float v = fmaf(tx0[q], e0[i], fmaf(tx1[q], e1[i],
                              fmaf(tx2[q], e2[i], xxn[q]))) + e3[i];
#pragma unroll
                    for (int jj = KSEL - 1; jj >= 1; --jj) a[jj] = med3f(v, a[jj - 1], a[jj]);
                    a[0] = fmaxf(a[0], v);
                }
            }
            float sel2 = 0.0f;
            for (int r = 0; r < KSEL; ++r) {
                float mx = a[0];
#pragma unroll
                for (int off = 32; off >= 1; off >>= 1) mx = fmaxf(mx, __shfl_xor(mx, off, 64));
                unsigned long long ball = __ballot(a[0] == mx);
                bool win = (lane == (int)__ffsll(ball) - 1);
#pragma unroll
                for (int jj = 0; jj < KSEL - 1; ++jj) a[jj] = win ? a[jj + 1] : a[jj];
                a[KSEL - 1] = win ? -3.0e38f : a[KSEL - 1];
                if (lane == r) sel2 = mx;
            }
            if (q == 0) selA = sel2; else selB = sel2;
        }
    }

    // exchange half top-20 lists through LDS
    if (lane < KSEL) {
        mxbuf[p][0][h][lane] = selA;
        mxbuf[p][1][h][lane] = selB;
    }
    __syncthreads();

    // final exact merge (merge-path formula); wave h handles query h of pair
    {
        const int q = h;
        float vA = (lane < KSEL) ? mxbuf[p][q][0][lane] : -3.0e38f;
        float vB = (lane < KSEL) ? mxbuf[p][q][1][lane] : -3.0e38f;
        float m = fmaxf(vA, vB);
#pragma unroll
        for (int j = 0; j < KSEL - 1; ++j) {
            float aj = __shfl(vA, j, 64);
            float bj = __shfl(vB, (lane - 1 - j) & 63, 64);
            float t = fminf(aj, bj);
            m = (j < lane) ? fmaxf(m, t) : m;
        }
        if (lane < KSEL) dfeat[(size_t)(qbase + q) * KSEL + lane] = m;
    }
}

// ---------- kernel: fused MLP (bn1/relu -> GEMM2 -> bn2/relu -> W3 -> sigmoid) ----------
__global__ __launch_bounds__(256) void k_mlp(const float* __restrict__ dfeat,
                                             const float* __restrict__ W1,
                                             const float* __restrict__ g1,
                                             const float* __restrict__ be1,
                                             const float* __restrict__ mu1,
                                             const float* __restrict__ va1,
                                             const float* __restrict__ W2T,
                                             const float* __restrict__ g2,
                                             const float* __restrict__ be2,
                                             const float* __restrict__ mu2,
                                             const float* __restrict__ va2,
                                             const float* __restrict__ W3,
                                             float* __restrict__ out) {
    __shared__ float h1l[32 * 260];               // 33,280 B (stride 260: conflict-free)
    const int t = threadIdx.x;
    const int rowbase = blockIdx.x * 32;          // grid 512 -> all 16384 rows

    float w[KSEL];
#pragma unroll
    for (int j = 0; j < KSEL; j += 4) {
        float4 q = *(const float4*)(W1 + t * KSEL + j);
        w[j] = q.x; w[j + 1] = q.y; w[j + 2] = q.z; w[j + 3] = q.w;
    }
    const float s1  = g1[t] * rsqrtf(va1[t] + 1e-5f);
    const float bc1 = be1[t] - mu1[t] * s1;

    for (int r = 0; r < 32; ++r) {
        const float* dr = dfeat + (size_t)(rowbase + r) * KSEL;
        float dv[KSEL];
#pragma unroll
        for (int j = 0; j < KSEL; j += 4) {
            float4 q = *(const float4*)(dr + j);
            dv[j] = q.x; dv[j + 1] = q.y; dv[j + 2] = q.z; dv[j + 3] = q.w;
        }
        float acc0 = 0.f, acc1 = 0.f;
#pragma unroll
        for (int j = 0; j < KSEL; j += 2) {
            acc0 = fmaf(w[j], dv[j], acc0);
            acc1 = fmaf(w[j + 1], dv[j + 1], acc1);
        }
        h1l[r * 260 + t] = fmaxf(0.f, fmaf(s1, acc0 + acc1, bc1));
    }
    __syncthreads();

    const int og = t & 15;
    const int rq = t >> 4;
    float acc[2][8];
#pragma unroll
    for (int r = 0; r < 2; ++r)
#pragma unroll
        for (int i = 0; i < 8; ++i) acc[r][i] = 0.f;

    for (int kq = 0; kq < 64; ++kq) {
        const int k = kq * 4;
        float4 hq[2];
#pragma unroll
        for (int rr = 0; rr < 2; ++rr)
            hq[rr] = *(const float4*)(&h1l[(rq * 2 + rr) * 260 + k]);
        float4 wq[8];
#pragma unroll
        for (int kk = 0; kk < 4; ++kk) {
            wq[kk]     = *(const float4*)(W2T + (k + kk) * 128 + og * 4);
            wq[4 + kk] = *(const float4*)(W2T + (k + kk) * 128 + 64 + og * 4);
        }
#pragma unroll
        for (int r = 0; r < 2; ++r) {
            const float* hh = (const float*)&hq[r];
#pragma unroll
            for (int kk = 0; kk < 4; ++kk) {
                const float hval = hh[kk];
                const float* w0 = (const float*)&wq[kk];
                const float* w1 = (const float*)&wq[4 + kk];
#pragma unroll
                for (int i = 0; i < 4; ++i) {
                    acc[r][i]     = fmaf(hval, w0[i], acc[r][i]);
                    acc[r][4 + i] = fmaf(hval, w1[i], acc[r][4 + i]);
                }
            }
        }
    }

    float s2v[8], b2v[8], w3v[8];
#pragma unroll
    for (int hh = 0; hh < 2; ++hh)
#pragma unroll
        for (int i = 0; i < 4; ++i) {
            const int o = hh * 64 + og * 4 + i;
            const float sv = g2[o] * rsqrtf(va2[o] + 1e-5f);
            s2v[hh * 4 + i] = sv;
            b2v[hh * 4 + i] = be2[o] - mu2[o] * sv;
            w3v[hh * 4 + i] = W3[o];
        }
#pragma unroll
    for (int r = 0; r < 2; ++r) {
        float c = 0.f;
#pragma unroll
        for (int i = 0; i < 8; ++i) {
            float h2 = fmaxf(0.f, fmaf(s2v[i], acc[r][i], b2v[i]));
            c = fmaf(w3v[i], h2, c);
        }
#pragma unroll
        for (int off = 8; off >= 1; off >>= 1) c += __shfl_xor(c, off, 64);
        if (og == 0) {
            out[rowbase + rq * 2 + r] = 1.0f / (1.0f + expf(-c));
        }
    }
}

extern "C" void kernel_launch(void* const* d_in, const int* in_sizes, int n_in,
                              void* d_out, int out_size, void* d_ws, size_t ws_size,
                              hipStream_t stream) {
    const float* x   = (const float*)d_in[0];
    const float* y   = (const float*)d_in[1];
    const float* W1  = (const float*)d_in[2];
    const float* g1  = (const float*)d_in[3];
    const float* be1 = (const float*)d_in[4];
    const float* mu1 = (const float*)d_in[5];
    const float* va1 = (const float*)d_in[6];
    const float* W2  = (const float*)d_in[7];
    const float* g2  = (const float*)d_in[8];
    const float* be2 = (const float*)d_in[9];
    const float* mu2 = (const float*)d_in[10];
    const float* va2 = (const float*)d_in[11];
    const float* W3  = (const float*)d_in[12];
    float* out = (float*)d_out;

    char* ws = (char*)d_ws;
    float* ys    = (float*)(ws);                                    // 262,144 B
    float* dfeat = (float*)(ws + 262144);                           // 1,310,720 B
    float* w2t   = (float*)(ws + 262144 + 1310720);                 // 131,072 B

    k_prep<<<192, 256, 0, stream>>>(y, W2, ys, w2t);
    k_knn <<<4096, 256, 0, stream>>>(x, ys, dfeat);
    k_mlp <<<512, 256, 0, stream>>>(dfeat, W1, g1, be1, mu1, va1,
                                    w2t, g2, be2, mu2, va2, W3, out);
}